// Round 6
// baseline (481.020 us; speedup 1.0000x reference)
//
#include <hip/hip_runtime.h>
#include <hip/hip_bf16.h>
#include <hip/hip_fp16.h>

#define NB 8
#define NN 256
#define KK 128
#define HH 32
#define DD 768

typedef _Float16 f16x8 __attribute__((ext_vector_type(8)));
typedef float f32x4 __attribute__((ext_vector_type(4)));

#if __has_builtin(__builtin_amdgcn_exp2f)
  #define EXP2(x) __builtin_amdgcn_exp2f(x)
#else
  #define EXP2(x) exp2f(x)
#endif
#if __has_builtin(__builtin_amdgcn_rcpf)
  #define RCP(x) __builtin_amdgcn_rcpf(x)
#else
  #define RCP(x) (1.0f / (x))
#endif

// W1 -> f16 row-major. W2 -> f16 with COLUMN PERMUTATION so that GEMM2's
// B-operand comes straight from GEMM1's accumulators:
// logical k = 32f+8g+ii maps to h-row 16*ii+4*g+f.
__global__ void prep_kernel(const float* __restrict__ l1_w,
                            const float* __restrict__ l2_w,
                            _Float16* __restrict__ w1h,
                            _Float16* __restrict__ w2h) {
  const int gid = blockIdx.x * 256 + threadIdx.x;
  if (gid < KK * KK) {
    w1h[gid] = (_Float16)l1_w[gid];
  } else if (gid < KK * KK + HH * KK) {
    const int g2 = gid - KK * KK;
    const int h = g2 >> 7, kl = g2 & 127;
    const int col = 16 * (kl & 7) + 4 * ((kl >> 3) & 3) + (kl >> 5);
    w2h[g2] = (_Float16)l2_w[h * KK + col];
  }
}

// Grid: 2048 blocks = (b, i). 256 thr = 4 waves.
// Per t (2 iters), block covers j in [t*128,(t+1)*128);
// wave w covers 32 j: jA = t*128 + w*32 + lr, jB = jA + 16.
__global__ __launch_bounds__(256, 3) void gbf_main_kernel(
    const float* __restrict__ pos, const float* __restrict__ means,
    const float* __restrict__ stds, const float* __restrict__ mul_w,
    const float* __restrict__ bias_w, const float* __restrict__ l1_b,
    const float* __restrict__ l2_b, const int* __restrict__ x,
    const int* __restrict__ nte, const _Float16* __restrict__ w1h,
    const _Float16* __restrict__ w2h, float* __restrict__ attn_out,
    float* __restrict__ s_out)
{
  // f16 tiles [row][col], 16B-group XOR swizzle: half_group ^= (row&7)
  __shared__ _Float16 w1s[KK * KK];       // 32 KB
  __shared__ _Float16 w2s[HH * KK];       // 8 KB (permuted contents)
  __shared__ __align__(16) f32x4 kt[KK];  // 2 KB: {mean, A, log2(kin), 0}
  __shared__ float ssp[4 * KK];           // 2 KB reduction scratch
  __shared__ float xvs[NN];               // 1 KB
  __shared__ unsigned char vms[NN];       // 256 B
  // total ~45.3 KB -> 3 blocks/CU

  const int bx = blockIdx.x;
  const int b = bx >> 8, i = bx & 255;
  const int tid = threadIdx.x;
  const int lane = tid & 63, w = tid >> 6;
  const int g = lane >> 4, lr = lane & 15;

  // ---- per-k constant table ----
  if (tid < KK) {
    const float sd = fabsf(stds[tid]) + 1e-5f;
    const float inv = 1.0f / sd;
    const float A = -0.72134752044448170f * inv * inv;  // -0.5*log2(e)/sd^2
    const float lk = log2f(inv * 0.3989424f);           // log2(1/(SQRT_2PI*sd))
    f32x4 v; v[0] = means[tid]; v[1] = A; v[2] = lk; v[3] = 0.f;
    kt[tid] = v;
  }
  vms[tid] = (x[b * NN + tid] != 0) ? 1 : 0;

  // ---- stage W1, W2 into LDS (f16, swizzled), 16B/thread/iter ----
  for (int idx = tid; idx < (KK * KK) / 8; idx += 256) {
    const int h = idx >> 4, k8 = idx & 15;
    const f16x8 v = *(const f16x8*)&w1h[idx * 8];
    *(f16x8*)&w1s[(h << 7) + ((k8 ^ (h & 7)) << 3)] = v;
  }
  for (int idx = tid; idx < (HH * KK) / 8; idx += 256) {
    const int h = idx >> 4, k8 = idx & 15;
    const f16x8 v = *(const f16x8*)&w2h[idx * 8];
    *(f16x8*)&w2s[(h << 7) + ((k8 ^ (h & 7)) << 3)] = v;
  }

  // ---- per-lane bias fragments from global (L2-resident) ----
  const f32x4* l1b4 = (const f32x4*)l1_b;
  const f32x4* l2b4 = (const f32x4*)l2_b;
  f32x4 bl[8];
#pragma unroll
  for (int ht = 0; ht < 8; ++ht) bl[ht] = l1b4[ht * 4 + g];  // l1_b[16ht+4g..+3]
  f32x4 bl2[2];
  bl2[0] = l2b4[g];      // l2_b[4g..+3]
  bl2[1] = l2b4[4 + g];  // l2_b[16+4g..+3]

  const bool valid_i = (x[b * NN + i] != 0);

  // ---- per-j xv ----
  {
    const int j = tid;
    const float pix = pos[(b * NN + i) * 3 + 0];
    const float piy = pos[(b * NN + i) * 3 + 1];
    const float piz = pos[(b * NN + i) * 3 + 2];
    const float dx = pos[(b * NN + j) * 3 + 0] - pix;
    const float dy = pos[(b * NN + j) * 3 + 1] - piy;
    const float dz = pos[(b * NN + j) * 3 + 2] - piz;
    const float sq = dx * dx + dy * dy + dz * dz;
    const float dist = (sq < 1e-4f) ? 100.0f : sqrtf(sq);
    const int base = ((b * NN + i) * NN + j) * 2;
    const int e0 = nte[base], e1 = nte[base + 1];
    const float mul = 0.5f * (mul_w[e0] + mul_w[e1]);
    const float bia = 0.5f * (bias_w[e0] + bias_w[e1]);
    xvs[j] = mul * dist + bia;
  }
  __syncthreads();  // staging + xvs complete; no further barriers until reduction

  float sp[32];
#pragma unroll
  for (int z = 0; z < 32; ++z) sp[z] = 0.0f;

  for (int t = 0; t < 2; ++t) {
    const int jA = t * 128 + w * 32 + lr;
    const int jB = jA + 16;
    const float xvA = xvs[jA], xvB = xvs[jB];
    const float mzA = (valid_i && vms[jA]) ? 0.0f : 1.0f;
    const float mzB = (valid_i && vms[jB]) ? 0.0f : 1.0f;

    // ---- gbf into 2 B-fragments; each kt read feeds both columns ----
    f16x8 afA[4], afB[4];
#pragma unroll
    for (int kf = 0; kf < 4; ++kf) {
#pragma unroll
      for (int ii = 0; ii < 8; ++ii) {
        const f32x4 c = kt[kf * 32 + g * 8 + ii];
        const float dA = xvA - c[0];
        const float eA = EXP2(__builtin_fmaf(c[1] * dA, dA, c[2]));
        const float dB = xvB - c[0];
        const float eB = EXP2(__builtin_fmaf(c[1] * dB, dB, c[2]));
        float s = sp[kf * 8 + ii];
        s = __builtin_fmaf(eA, mzA, s);
        s = __builtin_fmaf(eB, mzB, s);
        sp[kf * 8 + ii] = s;
        afA[kf][ii] = (_Float16)eA;
        afB[kf][ii] = (_Float16)eB;
      }
    }

    // ---- GEMM1 (swapped): each W1 fragment read feeds 2 MFMAs; fused gelu ----
    f16x8 paA[4], paB[4];
#pragma unroll
    for (int ht = 0; ht < 8; ++ht) {
      f32x4 aA = {0.f, 0.f, 0.f, 0.f};
      f32x4 aB = {0.f, 0.f, 0.f, 0.f};
#pragma unroll
      for (int kf = 0; kf < 4; ++kf) {
        const int row = ht * 16 + lr;
        const int kh = (kf * 32 + g * 8) ^ ((row & 7) << 3);
        const f16x8 bf = *(const f16x8*)&w1s[(row << 7) + kh];
        aA = __builtin_amdgcn_mfma_f32_16x16x32_f16(bf, afA[kf], aA, 0, 0, 0);
        aB = __builtin_amdgcn_mfma_f32_16x16x32_f16(bf, afB[kf], aB, 0, 0, 0);
      }
#pragma unroll
      for (int f = 0; f < 4; ++f) {
        {
          const float xh = aA[f] + bl[ht][f];
          const float u = xh * __builtin_fmaf(0.035677408f, xh * xh, 0.79788456f);
          const float tt = EXP2(fminf(u * 2.8853901f, 120.0f));
          paA[f][ht] = (_Float16)(xh * tt * RCP(1.0f + tt));
        }
        {
          const float xh = aB[f] + bl[ht][f];
          const float u = xh * __builtin_fmaf(0.035677408f, xh * xh, 0.79788456f);
          const float tt = EXP2(fminf(u * 2.8853901f, 120.0f));
          paB[f][ht] = (_Float16)(xh * tt * RCP(1.0f + tt));
        }
      }
    }

    // ---- GEMM2: each W2 fragment read feeds 2 MFMAs; direct global stores ----
#pragma unroll
    for (int nt2 = 0; nt2 < 2; ++nt2) {
      f32x4 cA = {0.f, 0.f, 0.f, 0.f};
      f32x4 cB = {0.f, 0.f, 0.f, 0.f};
#pragma unroll
      for (int f = 0; f < 4; ++f) {
        const int row = nt2 * 16 + lr;
        const int kh = (f * 32 + g * 8) ^ ((row & 7) << 3);
        const f16x8 wf = *(const f16x8*)&w2s[(row << 7) + kh];
        cA = __builtin_amdgcn_mfma_f32_16x16x32_f16(wf, paA[f], cA, 0, 0, 0);
        cB = __builtin_amdgcn_mfma_f32_16x16x32_f16(wf, paB[f], cB, 0, 0, 0);
      }
#pragma unroll
      for (int q = 0; q < 4; ++q) {
        const int hout = nt2 * 16 + g * 4 + q;
        const int base = (b * HH + hout) * (NN * NN) + i * NN + t * 128 + w * 32;
        attn_out[base + lr]      = (cA[q] + bl2[nt2][q]) * mzA;  // line written
        attn_out[base + 16 + lr] = (cB[q] + bl2[nt2][q]) * mzB;  // by one wave
      }
    }
  }

  // ---- dist_emb partials ----
#pragma unroll
  for (int z = 0; z < 32; ++z) {
    float v = sp[z];
    v += __shfl_xor(v, 1);
    v += __shfl_xor(v, 2);
    v += __shfl_xor(v, 4);
    v += __shfl_xor(v, 8);
    if (lr == 0) ssp[w * KK + (z >> 3) * 32 + g * 8 + (z & 7)] = v;
  }
  __syncthreads();
  if (tid < KK) {
    s_out[((b * NN + i) << 7) + tid] =
        ssp[tid] + ssp[KK + tid] + ssp[2 * KK + tid] + ssp[3 * KK + tid];
  }
}

// dist_emb = (S @ ep_w^T + ep_b) / 100 ; S is (2048 x 128) fp32.
// Tiled fp32 GEMM: 64(M) x 32(N) tiles, K split in 2; grid (32,24)=768 blocks.
__global__ __launch_bounds__(256, 3) void emb_kernel(
    const float* __restrict__ s_in, const float* __restrict__ ep_w,
    const float* __restrict__ ep_b, float* __restrict__ out)
{
  __shared__ float st[64][68];  // S^T sub-tile: st[kk][m], +4 pad
  __shared__ float wt[64][36];  // W^T sub-tile: wt[kk][n], +4 pad
  const int tid = threadIdx.x;
  const int r0 = blockIdx.x * 64;
  const int c0 = blockIdx.y * 32;
  const int m0 = tid >> 4, n0 = tid & 15;  // rows 4*m0..+3, cols 2*n0..+1

  float acc[4][2];
#pragma unroll
  for (int rr = 0; rr < 4; ++rr) { acc[rr][0] = 0.f; acc[rr][1] = 0.f; }

  for (int kp = 0; kp < 2; ++kp) {
    const int mrow = tid >> 4, k4 = tid & 15;  // staging map
#pragma unroll
    for (int mb = 0; mb < 64; mb += 16) {
      const float4 v = *(const float4*)&s_in[(r0 + mb + mrow) * KK + kp * 64 + k4 * 4];
      st[k4 * 4 + 0][mb + mrow] = v.x;
      st[k4 * 4 + 1][mb + mrow] = v.y;
      st[k4 * 4 + 2][mb + mrow] = v.z;
      st[k4 * 4 + 3][mb + mrow] = v.w;
    }
#pragma unroll
    for (int nb = 0; nb < 32; nb += 16) {
      const float4 u = *(const float4*)&ep_w[(c0 + nb + mrow) * KK + kp * 64 + k4 * 4];
      wt[k4 * 4 + 0][nb + mrow] = u.x;
      wt[k4 * 4 + 1][nb + mrow] = u.y;
      wt[k4 * 4 + 2][nb + mrow] = u.z;
      wt[k4 * 4 + 3][nb + mrow] = u.w;
    }
    __syncthreads();
#pragma unroll 4
    for (int kk = 0; kk < 64; ++kk) {
      const float4 sv = *(const float4*)&st[kk][m0 * 4];
      const float2 wv = *(const float2*)&wt[kk][n0 * 2];
      acc[0][0] = __builtin_fmaf(sv.x, wv.x, acc[0][0]);
      acc[0][1] = __builtin_fmaf(sv.x, wv.y, acc[0][1]);
      acc[1][0] = __builtin_fmaf(sv.y, wv.x, acc[1][0]);
      acc[1][1] = __builtin_fmaf(sv.y, wv.y, acc[1][1]);
      acc[2][0] = __builtin_fmaf(sv.z, wv.x, acc[2][0]);
      acc[2][1] = __builtin_fmaf(sv.z, wv.y, acc[2][1]);
      acc[3][0] = __builtin_fmaf(sv.w, wv.x, acc[3][0]);
      acc[3][1] = __builtin_fmaf(sv.w, wv.y, acc[3][1]);
    }
    __syncthreads();
  }

  const float2 bb = *(const float2*)&ep_b[c0 + n0 * 2];
#pragma unroll
  for (int rr = 0; rr < 4; ++rr) {
    float2 o;
    o.x = (acc[rr][0] + bb.x) * 0.01f;
    o.y = (acc[rr][1] + bb.y) * 0.01f;
    *(float2*)&out[(r0 + m0 * 4 + rr) * DD + c0 + n0 * 2] = o;
  }
}

extern "C" void kernel_launch(void* const* d_in, const int* in_sizes, int n_in,
                              void* d_out, int out_size, void* d_ws, size_t ws_size,
                              hipStream_t stream) {
  const float* pos    = (const float*)d_in[0];
  const float* means  = (const float*)d_in[1];
  const float* stds   = (const float*)d_in[2];
  const float* mul_w  = (const float*)d_in[3];
  const float* bias_w = (const float*)d_in[4];
  const float* l1_w   = (const float*)d_in[5];
  const float* l1_b   = (const float*)d_in[6];
  const float* l2_w   = (const float*)d_in[7];
  const float* l2_b   = (const float*)d_in[8];
  const float* ep_w   = (const float*)d_in[9];
  const float* ep_b   = (const float*)d_in[10];
  const int*   x      = (const int*)d_in[11];
  const int*   nte    = (const int*)d_in[12];

  float* out      = (float*)d_out;
  float* dist_emb = out;                 // (8,256,768)
  float* attn     = out + NB * NN * DD;  // (8,32,256,256)

  _Float16* w1h = (_Float16*)d_ws;                   // 32 KB
  _Float16* w2h = (_Float16*)((char*)d_ws + 32768);  // 8 KB (permuted)
  float*    s_ws = (float*)((char*)d_ws + 49152);    // 1 MB

  hipLaunchKernelGGL(prep_kernel, dim3(80), dim3(256), 0, stream,
                     l1_w, l2_w, w1h, w2h);
  hipLaunchKernelGGL(gbf_main_kernel, dim3(2048), dim3(256), 0, stream,
                     pos, means, stds, mul_w, bias_w, l1_b, l2_b,
                     x, nte, w1h, w2h, attn, s_ws);
  hipLaunchKernelGGL(emb_kernel, dim3(32, 24), dim3(256), 0, stream,
                     s_ws, ep_w, ep_b, dist_emb);
}

// Round 7
// 371.696 us; speedup vs baseline: 1.2941x; 1.2941x over previous
//
#include <hip/hip_runtime.h>
#include <hip/hip_bf16.h>
#include <hip/hip_fp16.h>

#define NB 8
#define NN 256
#define KK 128
#define HH 32
#define DD 768

typedef _Float16 f16x8 __attribute__((ext_vector_type(8)));
typedef float f32x4 __attribute__((ext_vector_type(4)));

#if __has_builtin(__builtin_amdgcn_exp2f)
  #define EXP2(x) __builtin_amdgcn_exp2f(x)
#else
  #define EXP2(x) exp2f(x)
#endif
#if __has_builtin(__builtin_amdgcn_rcpf)
  #define RCP(x) __builtin_amdgcn_rcpf(x)
#else
  #define RCP(x) (1.0f / (x))
#endif

// W1 -> f16 row-major. W2 -> f16 with COLUMN PERMUTATION so that GEMM2's
// B-operand comes straight from GEMM1's accumulators:
// logical k = 32f+8g+ii maps to h-row 16*ii+4*g+f.
__global__ void prep_kernel(const float* __restrict__ l1_w,
                            const float* __restrict__ l2_w,
                            _Float16* __restrict__ w1h,
                            _Float16* __restrict__ w2h) {
  const int gid = blockIdx.x * 256 + threadIdx.x;
  if (gid < KK * KK) {
    w1h[gid] = (_Float16)l1_w[gid];
  } else if (gid < KK * KK + HH * KK) {
    const int g2 = gid - KK * KK;
    const int h = g2 >> 7, kl = g2 & 127;
    const int col = 16 * (kl & 7) + 4 * ((kl >> 3) & 3) + (kl >> 5);
    w2h[g2] = (_Float16)l2_w[h * KK + col];
  }
}

// Grid: 2048 blocks = (b, i). 256 thr = 4 waves.
// Per t (2 iters), block covers j in [t*128,(t+1)*128);
// wave w covers 32 j: jA = t*128 + w*32 + lr, jB = jA + 16.
__global__ __launch_bounds__(256, 3) void gbf_main_kernel(
    const float* __restrict__ pos, const float* __restrict__ means,
    const float* __restrict__ stds, const float* __restrict__ mul_w,
    const float* __restrict__ bias_w, const float* __restrict__ l1_b,
    const float* __restrict__ l2_b, const int* __restrict__ x,
    const int* __restrict__ nte, const _Float16* __restrict__ w1h,
    const _Float16* __restrict__ w2h, float* __restrict__ attn_out,
    float* __restrict__ s_out)
{
  // f16 tiles [row][col], 16B-group XOR swizzle: half_group ^= (row&7)
  __shared__ _Float16 w1s[KK * KK];       // 32 KB
  __shared__ _Float16 w2s[HH * KK];       // 8 KB (permuted contents)
  __shared__ __align__(16) f32x4 kt[KK];  // 2 KB: {mean, A, log2(kin), 0}
  __shared__ __align__(16) float scratch[4 * 16 * 36];  // 9 KB: watt tiles / ssp
  __shared__ float xvs[NN];               // 1 KB
  __shared__ unsigned char vms[NN];       // 256 B
  // total ~52.2 KB -> 3 blocks/CU

  const int bx = blockIdx.x;
  const int b = bx >> 8, i = bx & 255;
  const int tid = threadIdx.x;
  const int lane = tid & 63, w = tid >> 6;
  const int g = lane >> 4, lr = lane & 15;

  // ---- per-k constant table ----
  if (tid < KK) {
    const float sd = fabsf(stds[tid]) + 1e-5f;
    const float inv = 1.0f / sd;
    const float A = -0.72134752044448170f * inv * inv;  // -0.5*log2(e)/sd^2
    const float lk = log2f(inv * 0.3989424f);           // log2(1/(SQRT_2PI*sd))
    f32x4 v; v[0] = means[tid]; v[1] = A; v[2] = lk; v[3] = 0.f;
    kt[tid] = v;
  }
  vms[tid] = (x[b * NN + tid] != 0) ? 1 : 0;

  // ---- stage W1, W2 into LDS (f16, swizzled), 16B/thread/iter ----
  for (int idx = tid; idx < (KK * KK) / 8; idx += 256) {
    const int h = idx >> 4, k8 = idx & 15;
    const f16x8 v = *(const f16x8*)&w1h[idx * 8];
    *(f16x8*)&w1s[(h << 7) + ((k8 ^ (h & 7)) << 3)] = v;
  }
  for (int idx = tid; idx < (HH * KK) / 8; idx += 256) {
    const int h = idx >> 4, k8 = idx & 15;
    const f16x8 v = *(const f16x8*)&w2h[idx * 8];
    *(f16x8*)&w2s[(h << 7) + ((k8 ^ (h & 7)) << 3)] = v;
  }

  // ---- per-lane bias fragments from global (L2-resident) ----
  const f32x4* l1b4 = (const f32x4*)l1_b;
  const f32x4* l2b4 = (const f32x4*)l2_b;
  f32x4 bl[8];
#pragma unroll
  for (int ht = 0; ht < 8; ++ht) bl[ht] = l1b4[ht * 4 + g];  // l1_b[16ht+4g..+3]
  f32x4 bl2[2];
  bl2[0] = l2b4[g];      // l2_b[4g..+3]
  bl2[1] = l2b4[4 + g];  // l2_b[16+4g..+3]

  const bool valid_i = (x[b * NN + i] != 0);

  // ---- per-j xv ----
  {
    const int j = tid;
    const float pix = pos[(b * NN + i) * 3 + 0];
    const float piy = pos[(b * NN + i) * 3 + 1];
    const float piz = pos[(b * NN + i) * 3 + 2];
    const float dx = pos[(b * NN + j) * 3 + 0] - pix;
    const float dy = pos[(b * NN + j) * 3 + 1] - piy;
    const float dz = pos[(b * NN + j) * 3 + 2] - piz;
    const float sq = dx * dx + dy * dy + dz * dz;
    const float dist = (sq < 1e-4f) ? 100.0f : sqrtf(sq);
    const int base = ((b * NN + i) * NN + j) * 2;
    const int e0 = nte[base], e1 = nte[base + 1];
    const float mul = 0.5f * (mul_w[e0] + mul_w[e1]);
    const float bia = 0.5f * (bias_w[e0] + bias_w[e1]);
    xvs[j] = mul * dist + bia;
  }
  __syncthreads();  // staging + xvs complete

  float* watt = &scratch[w * 576];  // wave-private [16][36] tile

  float sp[32];
#pragma unroll
  for (int z = 0; z < 32; ++z) sp[z] = 0.0f;

  for (int t = 0; t < 2; ++t) {
    const int jA = t * 128 + w * 32 + lr;
    const int jB = jA + 16;
    const float xvA = xvs[jA], xvB = xvs[jB];
    const float mzA = (valid_i && vms[jA]) ? 0.0f : 1.0f;
    const float mzB = (valid_i && vms[jB]) ? 0.0f : 1.0f;

    // ---- gbf into 2 B-fragments; each kt read feeds both columns ----
    f16x8 afA[4], afB[4];
#pragma unroll
    for (int kf = 0; kf < 4; ++kf) {
#pragma unroll
      for (int ii = 0; ii < 8; ++ii) {
        const f32x4 c = kt[kf * 32 + g * 8 + ii];
        const float dA = xvA - c[0];
        const float eA = EXP2(__builtin_fmaf(c[1] * dA, dA, c[2]));
        const float dB = xvB - c[0];
        const float eB = EXP2(__builtin_fmaf(c[1] * dB, dB, c[2]));
        float s = sp[kf * 8 + ii];
        s = __builtin_fmaf(eA, mzA, s);
        s = __builtin_fmaf(eB, mzB, s);
        sp[kf * 8 + ii] = s;
        afA[kf][ii] = (_Float16)eA;
        afB[kf][ii] = (_Float16)eB;
      }
    }

    // ---- GEMM1 (swapped): each W1 fragment read feeds 2 MFMAs; fused gelu ----
    f16x8 paA[4], paB[4];
#pragma unroll
    for (int ht = 0; ht < 8; ++ht) {
      f32x4 aA = {0.f, 0.f, 0.f, 0.f};
      f32x4 aB = {0.f, 0.f, 0.f, 0.f};
#pragma unroll
      for (int kf = 0; kf < 4; ++kf) {
        const int row = ht * 16 + lr;
        const int kh = (kf * 32 + g * 8) ^ ((row & 7) << 3);
        const f16x8 bf = *(const f16x8*)&w1s[(row << 7) + kh];
        aA = __builtin_amdgcn_mfma_f32_16x16x32_f16(bf, afA[kf], aA, 0, 0, 0);
        aB = __builtin_amdgcn_mfma_f32_16x16x32_f16(bf, afB[kf], aB, 0, 0, 0);
      }
#pragma unroll
      for (int f = 0; f < 4; ++f) {
        {
          const float xh = aA[f] + bl[ht][f];
          const float u = xh * __builtin_fmaf(0.035677408f, xh * xh, 0.79788456f);
          const float tt = EXP2(fminf(u * 2.8853901f, 120.0f));
          paA[f][ht] = (_Float16)(xh * tt * RCP(1.0f + tt));
        }
        {
          const float xh = aB[f] + bl[ht][f];
          const float u = xh * __builtin_fmaf(0.035677408f, xh * xh, 0.79788456f);
          const float tt = EXP2(fminf(u * 2.8853901f, 120.0f));
          paB[f][ht] = (_Float16)(xh * tt * RCP(1.0f + tt));
        }
      }
    }

    // ---- GEMM2 + wave-private staging + full-line flush ----
#pragma unroll
    for (int nt2 = 0; nt2 < 2; ++nt2) {
      f32x4 cA = {0.f, 0.f, 0.f, 0.f};
      f32x4 cB = {0.f, 0.f, 0.f, 0.f};
#pragma unroll
      for (int f = 0; f < 4; ++f) {
        const int row = nt2 * 16 + lr;
        const int kh = (f * 32 + g * 8) ^ ((row & 7) << 3);
        const f16x8 wf = *(const f16x8*)&w2s[(row << 7) + kh];
        cA = __builtin_amdgcn_mfma_f32_16x16x32_f16(wf, paA[f], cA, 0, 0, 0);
        cB = __builtin_amdgcn_mfma_f32_16x16x32_f16(wf, paB[f], cB, 0, 0, 0);
      }
      // stage: plane p = g*4+q (within this nt2 half), cols lr / lr+16
#pragma unroll
      for (int q = 0; q < 4; ++q) {
        const int p = g * 4 + q;
        watt[p * 36 + lr]      = (cA[q] + bl2[nt2][q]) * mzA;
        watt[p * 36 + 16 + lr] = (cB[q] + bl2[nt2][q]) * mzB;
      }
      // flush: 8 lanes x 16B = one full 128B line per plane per instruction
#pragma unroll
      for (int it = 0; it < 2; ++it) {
        const int p = it * 8 + (lane >> 3);
        const int c = lane & 7;
        const f32x4 v = *(const f32x4*)&watt[p * 36 + c * 4];
        *(f32x4*)&attn_out[(b * HH + nt2 * 16 + p) * (NN * NN) +
                           i * NN + t * 128 + w * 32 + c * 4] = v;
      }
    }
  }

  // ---- dist_emb partials (ssp overlays watt scratch -> barrier first) ----
  __syncthreads();
  float* ssp = scratch;
#pragma unroll
  for (int z = 0; z < 32; ++z) {
    float v = sp[z];
    v += __shfl_xor(v, 1);
    v += __shfl_xor(v, 2);
    v += __shfl_xor(v, 4);
    v += __shfl_xor(v, 8);
    if (lr == 0) ssp[w * KK + (z >> 3) * 32 + g * 8 + (z & 7)] = v;
  }
  __syncthreads();
  if (tid < KK) {
    s_out[((b * NN + i) << 7) + tid] =
        ssp[tid] + ssp[KK + tid] + ssp[2 * KK + tid] + ssp[3 * KK + tid];
  }
}

// dist_emb = (S @ ep_w^T + ep_b) / 100 ; S is (2048 x 128) fp32.
// Tiled fp32 GEMM: 64(M) x 32(N) tiles, K split in 2; grid (32,24)=768 blocks.
__global__ __launch_bounds__(256, 3) void emb_kernel(
    const float* __restrict__ s_in, const float* __restrict__ ep_w,
    const float* __restrict__ ep_b, float* __restrict__ out)
{
  __shared__ float st[64][68];  // S^T sub-tile: st[kk][m], +4 pad
  __shared__ float wt[64][36];  // W^T sub-tile: wt[kk][n], +4 pad
  const int tid = threadIdx.x;
  const int r0 = blockIdx.x * 64;
  const int c0 = blockIdx.y * 32;
  const int m0 = tid >> 4, n0 = tid & 15;  // rows 4*m0..+3, cols 2*n0..+1

  float acc[4][2];
#pragma unroll
  for (int rr = 0; rr < 4; ++rr) { acc[rr][0] = 0.f; acc[rr][1] = 0.f; }

  for (int kp = 0; kp < 2; ++kp) {
    const int mrow = tid >> 4, k4 = tid & 15;  // staging map
#pragma unroll
    for (int mb = 0; mb < 64; mb += 16) {
      const float4 v = *(const float4*)&s_in[(r0 + mb + mrow) * KK + kp * 64 + k4 * 4];
      st[k4 * 4 + 0][mb + mrow] = v.x;
      st[k4 * 4 + 1][mb + mrow] = v.y;
      st[k4 * 4 + 2][mb + mrow] = v.z;
      st[k4 * 4 + 3][mb + mrow] = v.w;
    }
#pragma unroll
    for (int nb = 0; nb < 32; nb += 16) {
      const float4 u = *(const float4*)&ep_w[(c0 + nb + mrow) * KK + kp * 64 + k4 * 4];
      wt[k4 * 4 + 0][nb + mrow] = u.x;
      wt[k4 * 4 + 1][nb + mrow] = u.y;
      wt[k4 * 4 + 2][nb + mrow] = u.z;
      wt[k4 * 4 + 3][nb + mrow] = u.w;
    }
    __syncthreads();
#pragma unroll 4
    for (int kk = 0; kk < 64; ++kk) {
      const float4 sv = *(const float4*)&st[kk][m0 * 4];
      const float2 wv = *(const float2*)&wt[kk][n0 * 2];
      acc[0][0] = __builtin_fmaf(sv.x, wv.x, acc[0][0]);
      acc[0][1] = __builtin_fmaf(sv.x, wv.y, acc[0][1]);
      acc[1][0] = __builtin_fmaf(sv.y, wv.x, acc[1][0]);
      acc[1][1] = __builtin_fmaf(sv.y, wv.y, acc[1][1]);
      acc[2][0] = __builtin_fmaf(sv.z, wv.x, acc[2][0]);
      acc[2][1] = __builtin_fmaf(sv.z, wv.y, acc[2][1]);
      acc[3][0] = __builtin_fmaf(sv.w, wv.x, acc[3][0]);
      acc[3][1] = __builtin_fmaf(sv.w, wv.y, acc[3][1]);
    }
    __syncthreads();
  }

  const float2 bb = *(const float2*)&ep_b[c0 + n0 * 2];
#pragma unroll
  for (int rr = 0; rr < 4; ++rr) {
    float2 o;
    o.x = (acc[rr][0] + bb.x) * 0.01f;
    o.y = (acc[rr][1] + bb.y) * 0.01f;
    *(float2*)&out[(r0 + m0 * 4 + rr) * DD + c0 + n0 * 2] = o;
  }
}

extern "C" void kernel_launch(void* const* d_in, const int* in_sizes, int n_in,
                              void* d_out, int out_size, void* d_ws, size_t ws_size,
                              hipStream_t stream) {
  const float* pos    = (const float*)d_in[0];
  const float* means  = (const float*)d_in[1];
  const float* stds   = (const float*)d_in[2];
  const float* mul_w  = (const float*)d_in[3];
  const float* bias_w = (const float*)d_in[4];
  const float* l1_w   = (const float*)d_in[5];
  const float* l1_b   = (const float*)d_in[6];
  const float* l2_w   = (const float*)d_in[7];
  const float* l2_b   = (const float*)d_in[8];
  const float* ep_w   = (const float*)d_in[9];
  const float* ep_b   = (const float*)d_in[10];
  const int*   x      = (const int*)d_in[11];
  const int*   nte    = (const int*)d_in[12];

  float* out      = (float*)d_out;
  float* dist_emb = out;                 // (8,256,768)
  float* attn     = out + NB * NN * DD;  // (8,32,256,256)

  _Float16* w1h = (_Float16*)d_ws;                   // 32 KB
  _Float16* w2h = (_Float16*)((char*)d_ws + 32768);  // 8 KB (permuted)
  float*    s_ws = (float*)((char*)d_ws + 49152);    // 1 MB

  hipLaunchKernelGGL(prep_kernel, dim3(80), dim3(256), 0, stream,
                     l1_w, l2_w, w1h, w2h);
  hipLaunchKernelGGL(gbf_main_kernel, dim3(2048), dim3(256), 0, stream,
                     pos, means, stds, mul_w, bias_w, l1_b, l2_b,
                     x, nte, w1h, w2h, attn, s_ws);
  hipLaunchKernelGGL(emb_kernel, dim3(32, 24), dim3(256), 0, stream,
                     s_ws, ep_w, ep_b, dist_emb);
}

// Round 8
// 105.749 us; speedup vs baseline: 4.5487x; 3.5149x over previous
//
#include <hip/hip_runtime.h>
#include <hip/hip_bf16.h>
#include <hip/hip_fp16.h>

#define NB 8
#define NN 256
#define KK 128
#define HH 32
#define DD 768

typedef _Float16 f16x8 __attribute__((ext_vector_type(8)));
typedef float f32x4 __attribute__((ext_vector_type(4)));

#if __has_builtin(__builtin_amdgcn_exp2f)
  #define EXP2(x) __builtin_amdgcn_exp2f(x)
#else
  #define EXP2(x) exp2f(x)
#endif
#if __has_builtin(__builtin_amdgcn_rcpf)
  #define RCP(x) __builtin_amdgcn_rcpf(x)
#else
  #define RCP(x) (1.0f / (x))
#endif

// W1 -> f16 row-major. W2 -> f16 with COLUMN PERMUTATION so that GEMM2's
// B-operand comes straight from GEMM1's accumulators:
// logical k = 32f+8g+ii maps to h-row 16*ii+4*g+f.
__global__ void prep_kernel(const float* __restrict__ l1_w,
                            const float* __restrict__ l2_w,
                            _Float16* __restrict__ w1h,
                            _Float16* __restrict__ w2h) {
  const int gid = blockIdx.x * 256 + threadIdx.x;
  if (gid < KK * KK) {
    w1h[gid] = (_Float16)l1_w[gid];
  } else if (gid < KK * KK + HH * KK) {
    const int g2 = gid - KK * KK;
    const int h = g2 >> 7, kl = g2 & 127;
    const int col = 16 * (kl & 7) + 4 * ((kl >> 3) & 3) + (kl >> 5);
    w2h[g2] = (_Float16)l2_w[h * KK + col];
  }
}

// Grid: 2048 blocks = (b, i). 256 thr = 4 waves.
// Per t (2 iters), block covers j in [t*128,(t+1)*128);
// wave w covers 32 j: jA = t*128 + w*32 + lr, jB = jA + 16.
__global__ __launch_bounds__(256, 3) void gbf_main_kernel(
    const float* __restrict__ pos, const float* __restrict__ means,
    const float* __restrict__ stds, const float* __restrict__ mul_w,
    const float* __restrict__ bias_w, const float* __restrict__ l1_b,
    const float* __restrict__ l2_b, const int* __restrict__ x,
    const int* __restrict__ nte, const _Float16* __restrict__ w1h,
    const _Float16* __restrict__ w2h, float* __restrict__ attn_out,
    float* __restrict__ s_out)
{
  // f16 tiles [row][col], 16B-group XOR swizzle: half_group ^= (row&7)
  __shared__ _Float16 w1s[KK * KK];                     // 32 KB
  __shared__ __align__(16) f32x4 kt[KK];                // 2 KB: {mean, A, log2(kin), 0}
  __shared__ __align__(16) float att[HH][132];          // 16.5 KB (overlaid by ssp)
  __shared__ float xvs[NN];                             // 1 KB
  __shared__ unsigned char vms[NN];                     // 256 B
  // total ~51.8 KB -> 3 blocks/CU

  const int bx = blockIdx.x;
  const int b = bx >> 8, i = bx & 255;
  const int tid = threadIdx.x;
  const int lane = tid & 63, w = tid >> 6;
  const int g = lane >> 4, lr = lane & 15;

  // ---- per-k constant table ----
  if (tid < KK) {
    const float sd = fabsf(stds[tid]) + 1e-5f;
    const float inv = 1.0f / sd;
    const float A = -0.72134752044448170f * inv * inv;  // -0.5*log2(e)/sd^2
    const float lk = log2f(inv * 0.3989424f);           // log2(1/(SQRT_2PI*sd))
    f32x4 v; v[0] = means[tid]; v[1] = A; v[2] = lk; v[3] = 0.f;
    kt[tid] = v;
  }
  vms[tid] = (x[b * NN + tid] != 0) ? 1 : 0;

  // ---- stage W1 into LDS (f16, swizzled), 16B/thread/iter ----
  for (int idx = tid; idx < (KK * KK) / 8; idx += 256) {
    const int h = idx >> 4, k8 = idx & 15;
    const f16x8 v = *(const f16x8*)&w1h[idx * 8];
    *(f16x8*)&w1s[(h << 7) + ((k8 ^ (h & 7)) << 3)] = v;
  }

  // ---- W2 fragments in registers (from permuted global copy, L2-hot) ----
  f16x8 wf2[2][4];
#pragma unroll
  for (int nt2 = 0; nt2 < 2; ++nt2)
#pragma unroll
    for (int f = 0; f < 4; ++f)
      wf2[nt2][f] = *(const f16x8*)&w2h[(nt2 * 16 + lr) * KK + f * 32 + g * 8];

  // ---- per-lane bias fragments from global (L2-resident) ----
  const f32x4* l1b4 = (const f32x4*)l1_b;
  const f32x4* l2b4 = (const f32x4*)l2_b;
  f32x4 bl[8];
#pragma unroll
  for (int ht = 0; ht < 8; ++ht) bl[ht] = l1b4[ht * 4 + g];  // l1_b[16ht+4g..+3]
  f32x4 bl2[2];
  bl2[0] = l2b4[g];      // l2_b[4g..+3]
  bl2[1] = l2b4[4 + g];  // l2_b[16+4g..+3]

  const bool valid_i = (x[b * NN + i] != 0);

  // ---- per-j xv ----
  {
    const int j = tid;
    const float pix = pos[(b * NN + i) * 3 + 0];
    const float piy = pos[(b * NN + i) * 3 + 1];
    const float piz = pos[(b * NN + i) * 3 + 2];
    const float dx = pos[(b * NN + j) * 3 + 0] - pix;
    const float dy = pos[(b * NN + j) * 3 + 1] - piy;
    const float dz = pos[(b * NN + j) * 3 + 2] - piz;
    const float sq = dx * dx + dy * dy + dz * dz;
    const float dist = (sq < 1e-4f) ? 100.0f : sqrtf(sq);
    const int base = ((b * NN + i) * NN + j) * 2;
    const int e0 = nte[base], e1 = nte[base + 1];
    const float mul = 0.5f * (mul_w[e0] + mul_w[e1]);
    const float bia = 0.5f * (bias_w[e0] + bias_w[e1]);
    xvs[j] = mul * dist + bia;
  }
  __syncthreads();  // staging + xvs complete

  float sp[32];
#pragma unroll
  for (int z = 0; z < 32; ++z) sp[z] = 0.0f;

  for (int t = 0; t < 2; ++t) {
    const int jA = t * 128 + w * 32 + lr;
    const int jB = jA + 16;
    const float xvA = xvs[jA], xvB = xvs[jB];
    const float mzA = (valid_i && vms[jA]) ? 0.0f : 1.0f;
    const float mzB = (valid_i && vms[jB]) ? 0.0f : 1.0f;

    // ---- gbf into 2 B-fragments; each kt read feeds both columns ----
    f16x8 afA[4], afB[4];
#pragma unroll
    for (int kf = 0; kf < 4; ++kf) {
#pragma unroll
      for (int ii = 0; ii < 8; ++ii) {
        const f32x4 c = kt[kf * 32 + g * 8 + ii];
        const float dA = xvA - c[0];
        const float eA = EXP2(__builtin_fmaf(c[1] * dA, dA, c[2]));
        const float dB = xvB - c[0];
        const float eB = EXP2(__builtin_fmaf(c[1] * dB, dB, c[2]));
        float s = sp[kf * 8 + ii];
        s = __builtin_fmaf(eA, mzA, s);
        s = __builtin_fmaf(eB, mzB, s);
        sp[kf * 8 + ii] = s;
        afA[kf][ii] = (_Float16)eA;
        afB[kf][ii] = (_Float16)eB;
      }
    }

    // ---- GEMM1 (swapped): each W1 fragment read feeds 2 MFMAs; fused gelu ----
    f16x8 paA[4], paB[4];
#pragma unroll
    for (int ht = 0; ht < 8; ++ht) {
      f32x4 aA = {0.f, 0.f, 0.f, 0.f};
      f32x4 aB = {0.f, 0.f, 0.f, 0.f};
#pragma unroll
      for (int kf = 0; kf < 4; ++kf) {
        const int row = ht * 16 + lr;
        const int kh = (kf * 32 + g * 8) ^ ((row & 7) << 3);
        const f16x8 bf = *(const f16x8*)&w1s[(row << 7) + kh];
        aA = __builtin_amdgcn_mfma_f32_16x16x32_f16(bf, afA[kf], aA, 0, 0, 0);
        aB = __builtin_amdgcn_mfma_f32_16x16x32_f16(bf, afB[kf], aB, 0, 0, 0);
      }
#pragma unroll
      for (int f = 0; f < 4; ++f) {
        {
          const float xh = aA[f] + bl[ht][f];
          const float u = xh * __builtin_fmaf(0.035677408f, xh * xh, 0.79788456f);
          const float tt = EXP2(fminf(u * 2.8853901f, 120.0f));
          paA[f][ht] = (_Float16)(xh * tt * RCP(1.0f + tt));
        }
        {
          const float xh = aB[f] + bl[ht][f];
          const float u = xh * __builtin_fmaf(0.035677408f, xh * xh, 0.79788456f);
          const float tt = EXP2(fminf(u * 2.8853901f, 120.0f));
          paB[f][ht] = (_Float16)(xh * tt * RCP(1.0f + tt));
        }
      }
    }

    // ---- GEMM2 (W2 fragments in registers) -> block att tile ----
#pragma unroll
    for (int nt2 = 0; nt2 < 2; ++nt2) {
      f32x4 cA = {0.f, 0.f, 0.f, 0.f};
      f32x4 cB = {0.f, 0.f, 0.f, 0.f};
#pragma unroll
      for (int f = 0; f < 4; ++f) {
        cA = __builtin_amdgcn_mfma_f32_16x16x32_f16(wf2[nt2][f], paA[f], cA, 0, 0, 0);
        cB = __builtin_amdgcn_mfma_f32_16x16x32_f16(wf2[nt2][f], paB[f], cB, 0, 0, 0);
      }
#pragma unroll
      for (int q = 0; q < 4; ++q) {
        const int p = nt2 * 16 + g * 4 + q;
        att[p][w * 32 + lr]      = (cA[q] + bl2[nt2][q]) * mzA;
        att[p][w * 32 + 16 + lr] = (cB[q] + bl2[nt2][q]) * mzB;
      }
    }
    __syncthreads();  // att tile complete

    // ---- flush: per wave-instr 2 planes x 512B contiguous, full sectors ----
#pragma unroll
    for (int it = 0; it < 4; ++it) {
      const int p = it * 8 + (tid >> 5);
      const int c = (tid & 31) * 4;
      const f32x4 v = *(const f32x4*)&att[p][c];
      *(f32x4*)&attn_out[(b * HH + p) * (NN * NN) + i * NN + t * 128 + c] = v;
    }
    __syncthreads();  // att consumed before next t overwrites
  }

  // ---- dist_emb partials (ssp overlays att -> already barriered) ----
  float* ssp = (float*)att;
#pragma unroll
  for (int z = 0; z < 32; ++z) {
    float v = sp[z];
    v += __shfl_xor(v, 1);
    v += __shfl_xor(v, 2);
    v += __shfl_xor(v, 4);
    v += __shfl_xor(v, 8);
    if (lr == 0) ssp[w * KK + (z >> 3) * 32 + g * 8 + (z & 7)] = v;
  }
  __syncthreads();
  if (tid < KK) {
    s_out[((b * NN + i) << 7) + tid] =
        ssp[tid] + ssp[KK + tid] + ssp[2 * KK + tid] + ssp[3 * KK + tid];
  }
}

// dist_emb = (S @ ep_w^T + ep_b) / 100 ; S is (2048 x 128) fp32.
// Tiled fp32 GEMM: 64(M) x 32(N) tiles, K split in 2; grid (32,24)=768 blocks.
__global__ __launch_bounds__(256, 3) void emb_kernel(
    const float* __restrict__ s_in, const float* __restrict__ ep_w,
    const float* __restrict__ ep_b, float* __restrict__ out)
{
  __shared__ float st[64][68];  // S^T sub-tile: st[kk][m], +4 pad
  __shared__ float wt[64][36];  // W^T sub-tile: wt[kk][n], +4 pad
  const int tid = threadIdx.x;
  const int r0 = blockIdx.x * 64;
  const int c0 = blockIdx.y * 32;
  const int m0 = tid >> 4, n0 = tid & 15;  // rows 4*m0..+3, cols 2*n0..+1

  float acc[4][2];
#pragma unroll
  for (int rr = 0; rr < 4; ++rr) { acc[rr][0] = 0.f; acc[rr][1] = 0.f; }

  for (int kp = 0; kp < 2; ++kp) {
    const int mrow = tid >> 4, k4 = tid & 15;  // staging map
#pragma unroll
    for (int mb = 0; mb < 64; mb += 16) {
      const float4 v = *(const float4*)&s_in[(r0 + mb + mrow) * KK + kp * 64 + k4 * 4];
      st[k4 * 4 + 0][mb + mrow] = v.x;
      st[k4 * 4 + 1][mb + mrow] = v.y;
      st[k4 * 4 + 2][mb + mrow] = v.z;
      st[k4 * 4 + 3][mb + mrow] = v.w;
    }
#pragma unroll
    for (int nb = 0; nb < 32; nb += 16) {
      const float4 u = *(const float4*)&ep_w[(c0 + nb + mrow) * KK + kp * 64 + k4 * 4];
      wt[k4 * 4 + 0][nb + mrow] = u.x;
      wt[k4 * 4 + 1][nb + mrow] = u.y;
      wt[k4 * 4 + 2][nb + mrow] = u.z;
      wt[k4 * 4 + 3][nb + mrow] = u.w;
    }
    __syncthreads();
#pragma unroll 4
    for (int kk = 0; kk < 64; ++kk) {
      const float4 sv = *(const float4*)&st[kk][m0 * 4];
      const float2 wv = *(const float2*)&wt[kk][n0 * 2];
      acc[0][0] = __builtin_fmaf(sv.x, wv.x, acc[0][0]);
      acc[0][1] = __builtin_fmaf(sv.x, wv.y, acc[0][1]);
      acc[1][0] = __builtin_fmaf(sv.y, wv.x, acc[1][0]);
      acc[1][1] = __builtin_fmaf(sv.y, wv.y, acc[1][1]);
      acc[2][0] = __builtin_fmaf(sv.z, wv.x, acc[2][0]);
      acc[2][1] = __builtin_fmaf(sv.z, wv.y, acc[2][1]);
      acc[3][0] = __builtin_fmaf(sv.w, wv.x, acc[3][0]);
      acc[3][1] = __builtin_fmaf(sv.w, wv.y, acc[3][1]);
    }
    __syncthreads();
  }

  const float2 bb = *(const float2*)&ep_b[c0 + n0 * 2];
#pragma unroll
  for (int rr = 0; rr < 4; ++rr) {
    float2 o;
    o.x = (acc[rr][0] + bb.x) * 0.01f;
    o.y = (acc[rr][1] + bb.y) * 0.01f;
    *(float2*)&out[(r0 + m0 * 4 + rr) * DD + c0 + n0 * 2] = o;
  }
}

extern "C" void kernel_launch(void* const* d_in, const int* in_sizes, int n_in,
                              void* d_out, int out_size, void* d_ws, size_t ws_size,
                              hipStream_t stream) {
  const float* pos    = (const float*)d_in[0];
  const float* means  = (const float*)d_in[1];
  const float* stds   = (const float*)d_in[2];
  const float* mul_w  = (const float*)d_in[3];
  const float* bias_w = (const float*)d_in[4];
  const float* l1_w   = (const float*)d_in[5];
  const float* l1_b   = (const float*)d_in[6];
  const float* l2_w   = (const float*)d_in[7];
  const float* l2_b   = (const float*)d_in[8];
  const float* ep_w   = (const float*)d_in[9];
  const float* ep_b   = (const float*)d_in[10];
  const int*   x      = (const int*)d_in[11];
  const int*   nte    = (const int*)d_in[12];

  float* out      = (float*)d_out;
  float* dist_emb = out;                 // (8,256,768)
  float* attn     = out + NB * NN * DD;  // (8,32,256,256)

  _Float16* w1h = (_Float16*)d_ws;                   // 32 KB
  _Float16* w2h = (_Float16*)((char*)d_ws + 32768);  // 8 KB (permuted)
  float*    s_ws = (float*)((char*)d_ws + 49152);    // 1 MB

  hipLaunchKernelGGL(prep_kernel, dim3(80), dim3(256), 0, stream,
                     l1_w, l2_w, w1h, w2h);
  hipLaunchKernelGGL(gbf_main_kernel, dim3(2048), dim3(256), 0, stream,
                     pos, means, stds, mul_w, bias_w, l1_b, l2_b,
                     x, nte, w1h, w2h, attn, s_ws);
  hipLaunchKernelGGL(emb_kernel, dim3(32, 24), dim3(256), 0, stream,
                     s_ws, ep_w, ep_b, dist_emb);
}

// Round 9
// 88.131 us; speedup vs baseline: 5.4580x; 1.1999x over previous
//
#include <hip/hip_runtime.h>
#include <hip/hip_bf16.h>
#include <hip/hip_fp16.h>

#define NB 8
#define NN 256
#define KK 128
#define HH 32
#define DD 768

typedef _Float16 f16x8 __attribute__((ext_vector_type(8)));
typedef float f32x4 __attribute__((ext_vector_type(4)));

#if __has_builtin(__builtin_amdgcn_exp2f)
  #define EXP2(x) __builtin_amdgcn_exp2f(x)
#else
  #define EXP2(x) exp2f(x)
#endif
#if __has_builtin(__builtin_amdgcn_rcpf)
  #define RCP(x) __builtin_amdgcn_rcpf(x)
#else
  #define RCP(x) (1.0f / (x))
#endif

// W1 -> f16 row-major. W2 -> f16 with COLUMN PERMUTATION so that GEMM2's
// B-operand comes straight from GEMM1's accumulators:
// logical k = 32f+8g+ii maps to h-row 16*ii+4*g+f.
__global__ void prep_kernel(const float* __restrict__ l1_w,
                            const float* __restrict__ l2_w,
                            _Float16* __restrict__ w1h,
                            _Float16* __restrict__ w2h) {
  const int gid = blockIdx.x * 256 + threadIdx.x;
  if (gid < KK * KK) {
    w1h[gid] = (_Float16)l1_w[gid];
  } else if (gid < KK * KK + HH * KK) {
    const int g2 = gid - KK * KK;
    const int h = g2 >> 7, kl = g2 & 127;
    const int col = 16 * (kl & 7) + 4 * ((kl >> 3) & 3) + (kl >> 5);
    w2h[g2] = (_Float16)l2_w[h * KK + col];
  }
}

// Grid: 2048 blocks = (b, i). 256 thr = 4 waves.
// Per t (2 iters), block covers j in [t*128,(t+1)*128);
// wave w covers 32 j as two columns: jA = t*128 + w*16 + lr, jB = jA + 64.
__global__ __launch_bounds__(256, 3) void gbf_main_kernel(
    const float* __restrict__ pos, const float* __restrict__ means,
    const float* __restrict__ stds, const float* __restrict__ mul_w,
    const float* __restrict__ bias_w, const float* __restrict__ l1_b,
    const float* __restrict__ l2_b, const int* __restrict__ x,
    const int* __restrict__ nte, const _Float16* __restrict__ w1h,
    const _Float16* __restrict__ w2h, float* __restrict__ attn_out,
    float* __restrict__ s_out)
{
  // f16 tiles [row][col], 16B-group XOR swizzle: half_group ^= (row&7)
  __shared__ _Float16 w1s[KK * KK];            // 32 KB
  __shared__ _Float16 w2s[HH * KK];            // 8 KB (permuted contents)
  __shared__ __align__(16) f32x4 kt[KK];       // 2 KB: {mean, A, log2(kin), 0}
  __shared__ __align__(16) float att[HH][68];  // 8.5 KB (overlaid by ssp)
  __shared__ float xvs[NN];                    // 1 KB
  __shared__ unsigned char vms[NN];            // 256 B
  // total ~51.8 KB -> 3 blocks/CU

  const int bx = blockIdx.x;
  const int b = bx >> 8, i = bx & 255;
  const int tid = threadIdx.x;
  const int lane = tid & 63, w = tid >> 6;
  const int g = lane >> 4, lr = lane & 15;

  // ---- per-k constant table ----
  if (tid < KK) {
    const float sd = fabsf(stds[tid]) + 1e-5f;
    const float inv = 1.0f / sd;
    const float A = -0.72134752044448170f * inv * inv;  // -0.5*log2(e)/sd^2
    const float lk = log2f(inv * 0.3989424f);           // log2(1/(SQRT_2PI*sd))
    f32x4 v; v[0] = means[tid]; v[1] = A; v[2] = lk; v[3] = 0.f;
    kt[tid] = v;
  }
  vms[tid] = (x[b * NN + tid] != 0) ? 1 : 0;

  // ---- stage W1, W2 into LDS (f16, swizzled), 16B/thread/iter ----
  for (int idx = tid; idx < (KK * KK) / 8; idx += 256) {
    const int h = idx >> 4, k8 = idx & 15;
    const f16x8 v = *(const f16x8*)&w1h[idx * 8];
    *(f16x8*)&w1s[(h << 7) + ((k8 ^ (h & 7)) << 3)] = v;
  }
  for (int idx = tid; idx < (HH * KK) / 8; idx += 256) {
    const int h = idx >> 4, k8 = idx & 15;
    const f16x8 v = *(const f16x8*)&w2h[idx * 8];
    *(f16x8*)&w2s[(h << 7) + ((k8 ^ (h & 7)) << 3)] = v;
  }

  // ---- per-lane bias fragments from global (L2-resident) ----
  const f32x4* l1b4 = (const f32x4*)l1_b;
  const f32x4* l2b4 = (const f32x4*)l2_b;
  f32x4 bl[8];
#pragma unroll
  for (int ht = 0; ht < 8; ++ht) bl[ht] = l1b4[ht * 4 + g];  // l1_b[16ht+4g..+3]
  f32x4 bl2[2];
  bl2[0] = l2b4[g];      // l2_b[4g..+3]
  bl2[1] = l2b4[4 + g];  // l2_b[16+4g..+3]

  const bool valid_i = (x[b * NN + i] != 0);

  // ---- per-j xv ----
  {
    const int j = tid;
    const float pix = pos[(b * NN + i) * 3 + 0];
    const float piy = pos[(b * NN + i) * 3 + 1];
    const float piz = pos[(b * NN + i) * 3 + 2];
    const float dx = pos[(b * NN + j) * 3 + 0] - pix;
    const float dy = pos[(b * NN + j) * 3 + 1] - piy;
    const float dz = pos[(b * NN + j) * 3 + 2] - piz;
    const float sq = dx * dx + dy * dy + dz * dz;
    const float dist = (sq < 1e-4f) ? 100.0f : sqrtf(sq);
    const int base = ((b * NN + i) * NN + j) * 2;
    const int e0 = nte[base], e1 = nte[base + 1];
    const float mul = 0.5f * (mul_w[e0] + mul_w[e1]);
    const float bia = 0.5f * (bias_w[e0] + bias_w[e1]);
    xvs[j] = mul * dist + bia;
  }
  __syncthreads();  // staging + xvs complete

  float sp[32];
#pragma unroll
  for (int z = 0; z < 32; ++z) sp[z] = 0.0f;

  for (int t = 0; t < 2; ++t) {
    const int jA = t * 128 + w * 16 + lr;  // cols [t*128, t*128+64)
    const int jB = jA + 64;                // cols [t*128+64, t*128+128)
    const float xvA = xvs[jA], xvB = xvs[jB];
    const float mzA = (valid_i && vms[jA]) ? 0.0f : 1.0f;
    const float mzB = (valid_i && vms[jB]) ? 0.0f : 1.0f;

    // ---- gbf into 2 B-fragments; each kt read feeds both columns ----
    f16x8 afA[4], afB[4];
#pragma unroll
    for (int kf = 0; kf < 4; ++kf) {
#pragma unroll
      for (int ii = 0; ii < 8; ++ii) {
        const f32x4 c = kt[kf * 32 + g * 8 + ii];
        const float dA = xvA - c[0];
        const float eA = EXP2(__builtin_fmaf(c[1] * dA, dA, c[2]));
        const float dB = xvB - c[0];
        const float eB = EXP2(__builtin_fmaf(c[1] * dB, dB, c[2]));
        float s = sp[kf * 8 + ii];
        s = __builtin_fmaf(eA, mzA, s);
        s = __builtin_fmaf(eB, mzB, s);
        sp[kf * 8 + ii] = s;
        afA[kf][ii] = (_Float16)eA;
        afB[kf][ii] = (_Float16)eB;
      }
    }

    // ---- GEMM1 (swapped): each W1 fragment read feeds 2 MFMAs; fused gelu ----
    f16x8 paA[4], paB[4];
#pragma unroll
    for (int ht = 0; ht < 8; ++ht) {
      f32x4 aA = {0.f, 0.f, 0.f, 0.f};
      f32x4 aB = {0.f, 0.f, 0.f, 0.f};
#pragma unroll
      for (int kf = 0; kf < 4; ++kf) {
        const int row = ht * 16 + lr;
        const int kh = (kf * 32 + g * 8) ^ ((row & 7) << 3);
        const f16x8 bf = *(const f16x8*)&w1s[(row << 7) + kh];
        aA = __builtin_amdgcn_mfma_f32_16x16x32_f16(bf, afA[kf], aA, 0, 0, 0);
        aB = __builtin_amdgcn_mfma_f32_16x16x32_f16(bf, afB[kf], aB, 0, 0, 0);
      }
#pragma unroll
      for (int f = 0; f < 4; ++f) {
        {
          const float xh = aA[f] + bl[ht][f];
          const float u = xh * __builtin_fmaf(0.035677408f, xh * xh, 0.79788456f);
          const float tt = EXP2(fminf(u * 2.8853901f, 120.0f));
          paA[f][ht] = (_Float16)(xh * tt * RCP(1.0f + tt));
        }
        {
          const float xh = aB[f] + bl[ht][f];
          const float u = xh * __builtin_fmaf(0.035677408f, xh * xh, 0.79788456f);
          const float tt = EXP2(fminf(u * 2.8853901f, 120.0f));
          paB[f][ht] = (_Float16)(xh * tt * RCP(1.0f + tt));
        }
      }
    }

    // ---- GEMM2: each W2 fragment read feeds 2 MFMAs ----
    f32x4 caA[2], caB[2];
#pragma unroll
    for (int nt2 = 0; nt2 < 2; ++nt2) {
      f32x4 cA = {0.f, 0.f, 0.f, 0.f};
      f32x4 cB = {0.f, 0.f, 0.f, 0.f};
#pragma unroll
      for (int f = 0; f < 4; ++f) {
        const int row = nt2 * 16 + lr;
        const int kh = (f * 32 + g * 8) ^ ((row & 7) << 3);
        const f16x8 wf = *(const f16x8*)&w2s[(row << 7) + kh];
        cA = __builtin_amdgcn_mfma_f32_16x16x32_f16(wf, paA[f], cA, 0, 0, 0);
        cB = __builtin_amdgcn_mfma_f32_16x16x32_f16(wf, paB[f], cB, 0, 0, 0);
      }
      caA[nt2] = cA;
      caB[nt2] = cB;
    }

    // ---- flush column-set A: R5-proven geometry (4 planes x 256B / wave-instr) ----
#pragma unroll
    for (int nt2 = 0; nt2 < 2; ++nt2)
#pragma unroll
      for (int q = 0; q < 4; ++q)
        att[nt2 * 16 + g * 4 + q][w * 16 + lr] = (caA[nt2][q] + bl2[nt2][q]) * mzA;
    __syncthreads();
#pragma unroll
    for (int rp = 0; rp < 2; ++rp) {
      const int plane = rp * 16 + (tid >> 4);
      const int jj = (tid & 15) * 4;
      const f32x4 v = *(const f32x4*)&att[plane][jj];
      *(f32x4*)&attn_out[(b * HH + plane) * (NN * NN) + i * NN + t * 128 + jj] = v;
    }
    __syncthreads();

    // ---- flush column-set B ----
#pragma unroll
    for (int nt2 = 0; nt2 < 2; ++nt2)
#pragma unroll
      for (int q = 0; q < 4; ++q)
        att[nt2 * 16 + g * 4 + q][w * 16 + lr] = (caB[nt2][q] + bl2[nt2][q]) * mzB;
    __syncthreads();
#pragma unroll
    for (int rp = 0; rp < 2; ++rp) {
      const int plane = rp * 16 + (tid >> 4);
      const int jj = (tid & 15) * 4;
      const f32x4 v = *(const f32x4*)&att[plane][jj];
      *(f32x4*)&attn_out[(b * HH + plane) * (NN * NN) + i * NN + t * 128 + 64 + jj] = v;
    }
    __syncthreads();
  }

  // ---- dist_emb partials (ssp overlays att -> already barriered) ----
  float* ssp = (float*)att;
#pragma unroll
  for (int z = 0; z < 32; ++z) {
    float v = sp[z];
    v += __shfl_xor(v, 1);
    v += __shfl_xor(v, 2);
    v += __shfl_xor(v, 4);
    v += __shfl_xor(v, 8);
    if (lr == 0) ssp[w * KK + (z >> 3) * 32 + g * 8 + (z & 7)] = v;
  }
  __syncthreads();
  if (tid < KK) {
    s_out[((b * NN + i) << 7) + tid] =
        ssp[tid] + ssp[KK + tid] + ssp[2 * KK + tid] + ssp[3 * KK + tid];
  }
}

// dist_emb = (S @ ep_w^T + ep_b) / 100 ; S is (2048 x 128) fp32.
// Tiled fp32 GEMM: 64(M) x 32(N) tiles, K split in 2; grid (32,24)=768 blocks.
__global__ __launch_bounds__(256, 3) void emb_kernel(
    const float* __restrict__ s_in, const float* __restrict__ ep_w,
    const float* __restrict__ ep_b, float* __restrict__ out)
{
  __shared__ float st[64][68];  // S^T sub-tile: st[kk][m], +4 pad
  __shared__ float wt[64][36];  // W^T sub-tile: wt[kk][n], +4 pad
  const int tid = threadIdx.x;
  const int r0 = blockIdx.x * 64;
  const int c0 = blockIdx.y * 32;
  const int m0 = tid >> 4, n0 = tid & 15;  // rows 4*m0..+3, cols 2*n0..+1

  float acc[4][2];
#pragma unroll
  for (int rr = 0; rr < 4; ++rr) { acc[rr][0] = 0.f; acc[rr][1] = 0.f; }

  for (int kp = 0; kp < 2; ++kp) {
    const int mrow = tid >> 4, k4 = tid & 15;  // staging map
#pragma unroll
    for (int mb = 0; mb < 64; mb += 16) {
      const float4 v = *(const float4*)&s_in[(r0 + mb + mrow) * KK + kp * 64 + k4 * 4];
      st[k4 * 4 + 0][mb + mrow] = v.x;
      st[k4 * 4 + 1][mb + mrow] = v.y;
      st[k4 * 4 + 2][mb + mrow] = v.z;
      st[k4 * 4 + 3][mb + mrow] = v.w;
    }
#pragma unroll
    for (int nb = 0; nb < 32; nb += 16) {
      const float4 u = *(const float4*)&ep_w[(c0 + nb + mrow) * KK + kp * 64 + k4 * 4];
      wt[k4 * 4 + 0][nb + mrow] = u.x;
      wt[k4 * 4 + 1][nb + mrow] = u.y;
      wt[k4 * 4 + 2][nb + mrow] = u.z;
      wt[k4 * 4 + 3][nb + mrow] = u.w;
    }
    __syncthreads();
#pragma unroll 4
    for (int kk = 0; kk < 64; ++kk) {
      const float4 sv = *(const float4*)&st[kk][m0 * 4];
      const float2 wv = *(const float2*)&wt[kk][n0 * 2];
      acc[0][0] = __builtin_fmaf(sv.x, wv.x, acc[0][0]);
      acc[0][1] = __builtin_fmaf(sv.x, wv.y, acc[0][1]);
      acc[1][0] = __builtin_fmaf(sv.y, wv.x, acc[1][0]);
      acc[1][1] = __builtin_fmaf(sv.y, wv.y, acc[1][1]);
      acc[2][0] = __builtin_fmaf(sv.z, wv.x, acc[2][0]);
      acc[2][1] = __builtin_fmaf(sv.z, wv.y, acc[2][1]);
      acc[3][0] = __builtin_fmaf(sv.w, wv.x, acc[3][0]);
      acc[3][1] = __builtin_fmaf(sv.w, wv.y, acc[3][1]);
    }
    __syncthreads();
  }

  const float2 bb = *(const float2*)&ep_b[c0 + n0 * 2];
#pragma unroll
  for (int rr = 0; rr < 4; ++rr) {
    float2 o;
    o.x = (acc[rr][0] + bb.x) * 0.01f;
    o.y = (acc[rr][1] + bb.y) * 0.01f;
    *(float2*)&out[(r0 + m0 * 4 + rr) * DD + c0 + n0 * 2] = o;
  }
}

extern "C" void kernel_launch(void* const* d_in, const int* in_sizes, int n_in,
                              void* d_out, int out_size, void* d_ws, size_t ws_size,
                              hipStream_t stream) {
  const float* pos    = (const float*)d_in[0];
  const float* means  = (const float*)d_in[1];
  const float* stds   = (const float*)d_in[2];
  const float* mul_w  = (const float*)d_in[3];
  const float* bias_w = (const float*)d_in[4];
  const float* l1_w   = (const float*)d_in[5];
  const float* l1_b   = (const float*)d_in[6];
  const float* l2_w   = (const float*)d_in[7];
  const float* l2_b   = (const float*)d_in[8];
  const float* ep_w   = (const float*)d_in[9];
  const float* ep_b   = (const float*)d_in[10];
  const int*   x      = (const int*)d_in[11];
  const int*   nte    = (const int*)d_in[12];

  float* out      = (float*)d_out;
  float* dist_emb = out;                 // (8,256,768)
  float* attn     = out + NB * NN * DD;  // (8,32,256,256)

  _Float16* w1h = (_Float16*)d_ws;                   // 32 KB
  _Float16* w2h = (_Float16*)((char*)d_ws + 32768);  // 8 KB (permuted)
  float*    s_ws = (float*)((char*)d_ws + 49152);    // 1 MB

  hipLaunchKernelGGL(prep_kernel, dim3(80), dim3(256), 0, stream,
                     l1_w, l2_w, w1h, w2h);
  hipLaunchKernelGGL(gbf_main_kernel, dim3(2048), dim3(256), 0, stream,
                     pos, means, stds, mul_w, bias_w, l1_b, l2_b,
                     x, nte, w1h, w2h, attn, s_ws);
  hipLaunchKernelGGL(emb_kernel, dim3(32, 24), dim3(256), 0, stream,
                     s_ws, ep_w, ep_b, dist_emb);
}